// Round 4
// baseline (632.491 us; speedup 1.0000x reference)
//
#include <hip/hip_runtime.h>

typedef __attribute__((ext_vector_type(4))) float f32x4;
typedef __attribute__((ext_vector_type(8))) short s16x8;

#define IN_F 512
#define OUT_F 512
#define STYLE_F 256

__device__ __forceinline__ unsigned short f2bf(float f) {
    unsigned int u = __builtin_bit_cast(unsigned int, f);
    u += 0x7FFFu + ((u >> 16) & 1u);   // round-to-nearest-even
    return (unsigned short)(u >> 16);
}

// pack 8 fp32 -> 8 bf16 (RNE) via v_cvt_pk_bf16_f32, 4 instrs
__device__ __forceinline__ s16x8 cvt8(const float4 a, const float4 b) {
    union { unsigned int w[4]; s16x8 v; } u;
    asm("v_cvt_pk_bf16_f32 %0, %1, %2" : "=v"(u.w[0]) : "v"(a.x), "v"(a.y));
    asm("v_cvt_pk_bf16_f32 %0, %1, %2" : "=v"(u.w[1]) : "v"(a.z), "v"(a.w));
    asm("v_cvt_pk_bf16_f32 %0, %1, %2" : "=v"(u.w[2]) : "v"(b.x), "v"(b.y));
    asm("v_cvt_pk_bf16_f32 %0, %1, %2" : "=v"(u.w[3]) : "v"(b.z), "v"(b.w));
    return u.v;
}

// ---------------- prep1: alpha/beta GEMVs (2048 dots of length 256) --------
__global__ __launch_bounds__(256) void prep1_kernel(
    const float* __restrict__ z,
    const float* __restrict__ w_alpha,
    const float* __restrict__ b_alpha,
    const float* __restrict__ w_beta,
    const float* __restrict__ b_beta,
    float* __restrict__ alpha,
    float* __restrict__ beta)
{
    int gid = blockIdx.x * 256 + threadIdx.x;
    if (gid >= 2048) return;
    int t = gid & 1023;
    int b = t >> 9;
    int i = t & 511;
    const float* zr = z + b * STYLE_F;
    const float* wr = (gid < 1024 ? w_alpha : w_beta) + i * STYLE_F;
    float acc = 0.f;
    #pragma unroll 4
    for (int kk = 0; kk < STYLE_F; kk += 4) {
        float4 zv = *reinterpret_cast<const float4*>(zr + kk);
        float4 vv = *reinterpret_cast<const float4*>(wr + kk);
        acc += zv.x * vv.x + zv.y * vv.y + zv.z * vv.z + zv.w * vv.w;
    }
    if (gid < 1024) alpha[t] = acc + b_alpha[i];
    else            beta[t]  = acc + b_beta[i];
}

// ---------------- prep2: W * alpha_b -> bf16 fragment order, per batch -----
// wfragB[b] element index = (((ks*32 + nf)*64 + lane)*8 + e)
//   holds weight[n = nf*16 + (lane&15)][k = ks*32 + (lane>>4)*8 + e] * alpha[b][k]
__global__ __launch_bounds__(256) void prep2_kernel(
    const float* __restrict__ weight,
    const float* __restrict__ alpha,
    unsigned short* __restrict__ wfragB)
{
    int gid = blockIdx.x * 256 + threadIdx.x;   // 131072 threads total
    int b = gid >> 16;                          // 65536 threads per batch
    int f = (gid & 65535) << 2;
    int e0 = f & 7;                 // 0 or 4
    int l  = (f >> 3) & 63;
    int nf = (f >> 9) & 31;
    int ks = f >> 14;               // 0..15
    int n  = nf * 16 + (l & 15);
    int k  = ks * 32 + ((l >> 4) << 3) + e0;
    float4 wv = *reinterpret_cast<const float4*>(weight + n * IN_F + k);
    float4 av = *reinterpret_cast<const float4*>(alpha + b * IN_F + k);
    ushort4 o;
    o.x = f2bf(wv.x * av.x); o.y = f2bf(wv.y * av.y);
    o.z = f2bf(wv.z * av.z); o.w = f2bf(wv.w * av.w);
    *reinterpret_cast<ushort4*>(wfragB + b * 262144 + f) = o;
}

// ---------------- main GEMM: out = x_bf16 @ (W*alpha_b)^T + beta -----------
// No LDS, no barriers. BM=64, BN=512 full, 8 waves (2M x 4N), wave tile
// 32x128 = 2x8 fragments. A: global->reg fp32, depth-3 pipeline, cvt_pk.
// B: L2-resident wfragB, global->reg, depth-1 pipeline.
__global__ __launch_bounds__(512, 2) void modlin_kernel(
    const float* __restrict__ x,
    const unsigned short* __restrict__ wfragB,
    const float* __restrict__ beta,
    float* __restrict__ out)
{
    const int tid = threadIdx.x;
    const int mb  = blockIdx.x;                 // 4096 blocks
    const long long row0 = (long long)mb * 64;
    const int b = mb >> 11;                     // 2048 blocks per batch

    // ---- wave / fragment map
    const int l  = tid & 63;
    const int w  = tid >> 6;
    const int wm = w >> 2;           // 0..1  (M)
    const int wn = w & 3;            // 0..3  (N)
    const int fr = l & 15;
    const int fq = l >> 4;           // 0..3

    // A row base pointers (this lane's 8 contiguous k-floats per slice)
    const float* xr0 = x + (row0 + wm * 32 + fr) * (long long)IN_F + fq * 8;
    const float* xr1 = xr0 + 16 * IN_F;

    // B fragment base (L2-resident)
    const unsigned short* bbase = wfragB + (size_t)b * 262144
                                + ((size_t)(wn * 8) * 64 + l) * 8;

    f32x4 acc[2][8];
    #pragma unroll
    for (int i = 0; i < 2; i++)
        #pragma unroll
        for (int j = 0; j < 8; j++)
            acc[i][j] = (f32x4){0.f, 0.f, 0.f, 0.f};

    float4 ax[4][4];     // A fp32 prefetch slots (depth 3)
    s16x8  bq[2][8];     // B prefetch slots (depth 1)

    #define LOADA(s, slot)                                                  \
        do {                                                                \
            const float* p0_ = xr0 + (s) * 32;                              \
            const float* p1_ = xr1 + (s) * 32;                              \
            ax[slot][0] = *reinterpret_cast<const float4*>(p0_);            \
            ax[slot][1] = *reinterpret_cast<const float4*>(p0_ + 4);        \
            ax[slot][2] = *reinterpret_cast<const float4*>(p1_);            \
            ax[slot][3] = *reinterpret_cast<const float4*>(p1_ + 4);        \
        } while (0)

    #define LOADB(s, slot)                                                  \
        do {                                                                \
            const unsigned short* bp_ = bbase + (s) * 16384;                \
            _Pragma("unroll")                                               \
            for (int nf_ = 0; nf_ < 8; nf_++)                               \
                bq[slot][nf_] =                                             \
                    *reinterpret_cast<const s16x8*>(bp_ + nf_ * 512);       \
        } while (0)

    // prologue: A slices 0..2 in flight, B slice 0 in flight
    LOADA(0, 0); LOADA(1, 1); LOADA(2, 2);
    LOADB(0, 0);

    // ---- 16 k-slices of 32, fully unrolled (static slot indices)
    #pragma unroll
    for (int s = 0; s < 16; s++) {
        if (s + 3 < 16) LOADA(s + 3, (s + 3) & 3);
        if (s + 1 < 16) LOADB(s + 1, (s + 1) & 1);

        s16x8 a0 = cvt8(ax[s & 3][0], ax[s & 3][1]);
        s16x8 a1 = cvt8(ax[s & 3][2], ax[s & 3][3]);

        #pragma unroll
        for (int nf = 0; nf < 8; nf++) {
            acc[0][nf] = __builtin_amdgcn_mfma_f32_16x16x32_bf16(
                a0, bq[s & 1][nf], acc[0][nf], 0, 0, 0);
            acc[1][nf] = __builtin_amdgcn_mfma_f32_16x16x32_bf16(
                a1, bq[s & 1][nf], acc[1][nf], 0, 0, 0);
        }
    }
    #undef LOADA
    #undef LOADB

    // ---- epilogue: add beta, store fp32
    const float* brow = beta + b * OUT_F;
    #pragma unroll
    for (int nf = 0; nf < 8; nf++) {
        int col = wn * 128 + nf * 16 + fr;
        float bv = brow[col];
        #pragma unroll
        for (int mf = 0; mf < 2; mf++) {
            long long r = row0 + wm * 32 + mf * 16 + fq * 4;
            float* op = out + r * OUT_F + col;
            op[0 * OUT_F] = acc[mf][nf][0] + bv;
            op[1 * OUT_F] = acc[mf][nf][1] + bv;
            op[2 * OUT_F] = acc[mf][nf][2] + bv;
            op[3 * OUT_F] = acc[mf][nf][3] + bv;
        }
    }
}

extern "C" void kernel_launch(void* const* d_in, const int* in_sizes, int n_in,
                              void* d_out, int out_size, void* d_ws, size_t ws_size,
                              hipStream_t stream)
{
    const float* x       = (const float*)d_in[0];
    const float* z       = (const float*)d_in[1];
    const float* weight  = (const float*)d_in[2];
    const float* w_alpha = (const float*)d_in[3];
    const float* b_alpha = (const float*)d_in[4];
    const float* w_beta  = (const float*)d_in[5];
    const float* b_beta  = (const float*)d_in[6];
    float* out = (float*)d_out;

    unsigned short* wfragB = (unsigned short*)d_ws;          // 2 x 512 KiB
    float* alpha = (float*)((char*)d_ws + 1048576);          // 4 KiB
    float* beta  = alpha + 2 * IN_F;                         // 4 KiB

    prep1_kernel<<<8, 256, 0, stream>>>(z, w_alpha, b_alpha, w_beta, b_beta,
                                        alpha, beta);
    prep2_kernel<<<512, 256, 0, stream>>>(weight, alpha, wfragB);
    modlin_kernel<<<4096, 512, 0, stream>>>(x, wfragB, beta, out);
}

// Round 5
// 364.351 us; speedup vs baseline: 1.7359x; 1.7359x over previous
//
#include <hip/hip_runtime.h>

typedef __attribute__((ext_vector_type(4))) float f32x4;
typedef __attribute__((ext_vector_type(8))) short s16x8;

#define IN_F 512
#define OUT_F 512
#define STYLE_F 256

typedef __attribute__((address_space(1))) const void gvoid;
typedef __attribute__((address_space(3))) void svoid;

__device__ __forceinline__ unsigned short f2bf(float f) {
    unsigned int u = __builtin_bit_cast(unsigned int, f);
    u += 0x7FFFu + ((u >> 16) & 1u);   // round-to-nearest-even
    return (unsigned short)(u >> 16);
}

// pack 8 fp32 -> 8 bf16 (RNE) via v_cvt_pk_bf16_f32
__device__ __forceinline__ s16x8 cvt8(f32x4 a, f32x4 b) {
    union { unsigned int w[4]; s16x8 v; } u;
    asm("v_cvt_pk_bf16_f32 %0, %1, %2" : "=v"(u.w[0]) : "v"(a[0]), "v"(a[1]));
    asm("v_cvt_pk_bf16_f32 %0, %1, %2" : "=v"(u.w[1]) : "v"(a[2]), "v"(a[3]));
    asm("v_cvt_pk_bf16_f32 %0, %1, %2" : "=v"(u.w[2]) : "v"(b[0]), "v"(b[1]));
    asm("v_cvt_pk_bf16_f32 %0, %1, %2" : "=v"(u.w[3]) : "v"(b[2]), "v"(b[3]));
    return u.v;
}

// ---------------- prep1: alpha/beta GEMVs (2048 dots of length 256) --------
__global__ __launch_bounds__(256) void prep1_kernel(
    const float* __restrict__ z,
    const float* __restrict__ w_alpha,
    const float* __restrict__ b_alpha,
    const float* __restrict__ w_beta,
    const float* __restrict__ b_beta,
    float* __restrict__ alpha,
    float* __restrict__ beta)
{
    int gid = blockIdx.x * 256 + threadIdx.x;
    if (gid >= 2048) return;
    int t = gid & 1023;
    int b = t >> 9;
    int i = t & 511;
    const float* zr = z + b * STYLE_F;
    const float* wr = (gid < 1024 ? w_alpha : w_beta) + i * STYLE_F;
    float acc = 0.f;
    #pragma unroll 4
    for (int kk = 0; kk < STYLE_F; kk += 4) {
        float4 zv = *reinterpret_cast<const float4*>(zr + kk);
        float4 vv = *reinterpret_cast<const float4*>(wr + kk);
        acc += zv.x * vv.x + zv.y * vv.y + zv.z * vv.z + zv.w * vv.w;
    }
    if (gid < 1024) alpha[t] = acc + b_alpha[i];
    else            beta[t]  = acc + b_beta[i];
}

// ---------------- prep2: W * alpha_b -> bf16 fragment order, per batch -----
// wfragB[b] element index = (((ks*32 + nf)*64 + lane)*8 + e)
//   holds weight[n = nf*16 + (lane&15)][k = ks*32 + (lane>>4)*8 + e] * alpha[b][k]
__global__ __launch_bounds__(256) void prep2_kernel(
    const float* __restrict__ weight,
    const float* __restrict__ alpha,
    unsigned short* __restrict__ wfragB)
{
    int gid = blockIdx.x * 256 + threadIdx.x;   // 131072 threads total
    int b = gid >> 16;                          // 65536 threads per batch
    int f = (gid & 65535) << 2;
    int e0 = f & 7;                 // 0 or 4
    int l  = (f >> 3) & 63;
    int nf = (f >> 9) & 31;
    int ks = f >> 14;               // 0..15
    int n  = nf * 16 + (l & 15);
    int k  = ks * 32 + ((l >> 4) << 3) + e0;
    float4 wv = *reinterpret_cast<const float4*>(weight + n * IN_F + k);
    float4 av = *reinterpret_cast<const float4*>(alpha + b * IN_F + k);
    ushort4 o;
    o.x = f2bf(wv.x * av.x); o.y = f2bf(wv.y * av.y);
    o.z = f2bf(wv.z * av.z); o.w = f2bf(wv.w * av.w);
    *reinterpret_cast<ushort4*>(wfragB + b * 262144 + f) = o;
}

// ---------------- main GEMM: out = x_bf16 @ (W*alpha_b)^T + beta -----------
// BM=32, BN=512 (full), BK=64, 8 K-steps. 512 thr = 8 waves, wave tile 32x64.
// A: global_load_lds fp32, 3 LDS buffers, counted-vmcnt manual pipeline.
// B: L2-resident wfragB via inline-asm global_load_dwordx4 (8/step/wave).
__global__ __launch_bounds__(512) void modlin_kernel(
    const float* __restrict__ x,
    const unsigned short* __restrict__ wfragB,
    const float* __restrict__ beta,
    float* __restrict__ out)
{
    // 3 bufs x (32 rows x 64k fp32 = 8 KiB). Unit = 16B. Unit u of row r
    // lives at slot s = u ^ (r&7):  byte = buf*8192 + r*256 + s*16.
    __shared__ __align__(16) char lds[3 * 8192];

    const int tid = threadIdx.x;
    const int mb  = blockIdx.x;               // 8192 blocks
    const long long row0 = (long long)mb * 32;
    const int b = mb >> 12;                   // 4096 blocks per batch

    // ---- DMA source map: thread tid fills slot tid -> (r = tid>>4, s = tid&15)
    const int r  = tid >> 4;                  // 0..31
    const int uu = (tid & 15) ^ (r & 7);      // pre-swizzled global unit
    const float* xsrc = x + (row0 + r) * IN_F + uu * 4;
    const int wvbase = (tid >> 6) << 10;      // wave-uniform LDS base (1KiB/wave)

    // ---- wave / fragment map (all waves share A rows 0..31)
    const int l  = tid & 63;
    const int wn = tid >> 6;                  // 0..7 (N position)
    const int fr = l & 15;
    const int fq = l >> 4;                    // 0..3

    // A ds_read base pointers (slice-unit variants; +4096 for mf=1, +(t%3)*8192 buf)
    const char* a00 = lds + fr * 256 + (((fq * 2)    ) ^ (fr & 7)) * 16; // s0,u0
    const char* a01 = lds + fr * 256 + (((fq * 2) + 1) ^ (fr & 7)) * 16; // s0,u1
    const char* a10 = lds + fr * 256 + ((8 + fq * 2  ) ^ (fr & 7)) * 16; // s1,u0
    const char* a11 = lds + fr * 256 + ((8 + fq * 2+1) ^ (fr & 7)) * 16; // s1,u1

    // B: byte offset of fragment (ks, nf=wn*4+j, lane l):
    //    ((ks*32 + wn*4 + j)*64 + l)*16 ; j via imm (1024), slice via +32768,
    //    step via +65536.
    const unsigned short* bb = wfragB + (size_t)b * 262144;
    const unsigned int voff0 = (unsigned int)(wn * 4096 + l * 16);

    f32x4 acc[2][4];
    #pragma unroll
    for (int i = 0; i < 2; i++)
        #pragma unroll
        for (int j = 0; j < 4; j++)
            acc[i][j] = (f32x4){0.f, 0.f, 0.f, 0.f};

    s16x8 bA0, bA1, bA2, bA3, bA4, bA5, bA6, bA7;

    #define ISSUE_DMA(tt)                                                    \
        __builtin_amdgcn_global_load_lds(                                    \
            (gvoid*)(xsrc + (tt) * 64),                                      \
            (svoid*)(lds + ((tt) % 3) * 8192 + wvbase), 16, 0, 0)

    #define LOADB(vo)                                                        \
        do {                                                                 \
            unsigned int vo0_ = (vo);                                        \
            unsigned int vo1_ = (vo) + 32768u;                               \
            asm volatile("global_load_dwordx4 %0, %1, %2 offset:0"           \
                : "=v"(bA0) : "v"(vo0_), "s"(bb) : "memory");                \
            asm volatile("global_load_dwordx4 %0, %1, %2 offset:1024"        \
                : "=v"(bA1) : "v"(vo0_), "s"(bb) : "memory");                \
            asm volatile("global_load_dwordx4 %0, %1, %2 offset:2048"        \
                : "=v"(bA2) : "v"(vo0_), "s"(bb) : "memory");                \
            asm volatile("global_load_dwordx4 %0, %1, %2 offset:3072"        \
                : "=v"(bA3) : "v"(vo0_), "s"(bb) : "memory");                \
            asm volatile("global_load_dwordx4 %0, %1, %2 offset:0"           \
                : "=v"(bA4) : "v"(vo1_), "s"(bb) : "memory");                \
            asm volatile("global_load_dwordx4 %0, %1, %2 offset:1024"        \
                : "=v"(bA5) : "v"(vo1_), "s"(bb) : "memory");                \
            asm volatile("global_load_dwordx4 %0, %1, %2 offset:2048"        \
                : "=v"(bA6) : "v"(vo1_), "s"(bb) : "memory");                \
            asm volatile("global_load_dwordx4 %0, %1, %2 offset:3072"        \
                : "=v"(bA7) : "v"(vo1_), "s"(bb) : "memory");                \
        } while (0)

    // ---- prologue: DMA(0), DMA(1), B(0) in flight; wait own DMA(0)
    ISSUE_DMA(0);
    ISSUE_DMA(1);
    LOADB(voff0);
    asm volatile("s_waitcnt vmcnt(9)" ::: "memory");   // DMA(0) done (9 younger)
    __builtin_amdgcn_sched_barrier(0);

    // ---- K loop, fully unrolled: per step exactly {8 B-loads, 1 DMA} issued
    #pragma unroll
    for (int t = 0; t < 8; ++t) {
        __builtin_amdgcn_s_barrier();          // raw: no implicit vmcnt(0)
        if (t >= 1) LOADB(voff0 + (unsigned)t * 65536u);
        if (t <= 5) ISSUE_DMA(t + 2);

        const int bo = (t % 3) * 8192;
        // slice 0
        f32x4 v0 = *(const f32x4*)(a00 + bo);
        f32x4 v1 = *(const f32x4*)(a01 + bo);
        f32x4 v2 = *(const f32x4*)(a00 + bo + 4096);
        f32x4 v3 = *(const f32x4*)(a01 + bo + 4096);
        s16x8 aS0M0 = cvt8(v0, v1);
        s16x8 aS0M1 = cvt8(v2, v3);
        // slice 1
        f32x4 w0 = *(const f32x4*)(a10 + bo);
        f32x4 w1 = *(const f32x4*)(a11 + bo);
        f32x4 w2 = *(const f32x4*)(a10 + bo + 4096);
        f32x4 w3 = *(const f32x4*)(a11 + bo + 4096);
        s16x8 aS1M0 = cvt8(w0, w1);
        s16x8 aS1M1 = cvt8(w2, w3);

        // wait: all B(t) + DMA(t+1) retired; DMA(t+2) (if issued) stays in flight
        if (t <= 5) asm volatile("s_waitcnt vmcnt(1)" ::: "memory");
        else        asm volatile("s_waitcnt vmcnt(0)" ::: "memory");
        __builtin_amdgcn_sched_barrier(0);

        acc[0][0] = __builtin_amdgcn_mfma_f32_16x16x32_bf16(aS0M0, bA0, acc[0][0], 0, 0, 0);
        acc[1][0] = __builtin_amdgcn_mfma_f32_16x16x32_bf16(aS0M1, bA0, acc[1][0], 0, 0, 0);
        acc[0][1] = __builtin_amdgcn_mfma_f32_16x16x32_bf16(aS0M0, bA1, acc[0][1], 0, 0, 0);
        acc[1][1] = __builtin_amdgcn_mfma_f32_16x16x32_bf16(aS0M1, bA1, acc[1][1], 0, 0, 0);
        acc[0][2] = __builtin_amdgcn_mfma_f32_16x16x32_bf16(aS0M0, bA2, acc[0][2], 0, 0, 0);
        acc[1][2] = __builtin_amdgcn_mfma_f32_16x16x32_bf16(aS0M1, bA2, acc[1][2], 0, 0, 0);
        acc[0][3] = __builtin_amdgcn_mfma_f32_16x16x32_bf16(aS0M0, bA3, acc[0][3], 0, 0, 0);
        acc[1][3] = __builtin_amdgcn_mfma_f32_16x16x32_bf16(aS0M1, bA3, acc[1][3], 0, 0, 0);
        acc[0][0] = __builtin_amdgcn_mfma_f32_16x16x32_bf16(aS1M0, bA4, acc[0][0], 0, 0, 0);
        acc[1][0] = __builtin_amdgcn_mfma_f32_16x16x32_bf16(aS1M1, bA4, acc[1][0], 0, 0, 0);
        acc[0][1] = __builtin_amdgcn_mfma_f32_16x16x32_bf16(aS1M0, bA5, acc[0][1], 0, 0, 0);
        acc[1][1] = __builtin_amdgcn_mfma_f32_16x16x32_bf16(aS1M1, bA5, acc[1][1], 0, 0, 0);
        acc[0][2] = __builtin_amdgcn_mfma_f32_16x16x32_bf16(aS1M0, bA6, acc[0][2], 0, 0, 0);
        acc[1][2] = __builtin_amdgcn_mfma_f32_16x16x32_bf16(aS1M1, bA6, acc[1][2], 0, 0, 0);
        acc[0][3] = __builtin_amdgcn_mfma_f32_16x16x32_bf16(aS1M0, bA7, acc[0][3], 0, 0, 0);
        acc[1][3] = __builtin_amdgcn_mfma_f32_16x16x32_bf16(aS1M1, bA7, acc[1][3], 0, 0, 0);
    }
    #undef ISSUE_DMA
    #undef LOADB

    // ---- epilogue: add beta, store fp32
    const float* brow = beta + b * OUT_F + wn * 64 + fr;
    #pragma unroll
    for (int nf = 0; nf < 4; nf++) {
        float bv = brow[nf * 16];
        #pragma unroll
        for (int mf = 0; mf < 2; mf++) {
            float* op = out + (row0 + mf * 16 + fq * 4) * OUT_F
                            + wn * 64 + nf * 16 + fr;
            op[0 * OUT_F] = acc[mf][nf][0] + bv;
            op[1 * OUT_F] = acc[mf][nf][1] + bv;
            op[2 * OUT_F] = acc[mf][nf][2] + bv;
            op[3 * OUT_F] = acc[mf][nf][3] + bv;
        }
    }
}

extern "C" void kernel_launch(void* const* d_in, const int* in_sizes, int n_in,
                              void* d_out, int out_size, void* d_ws, size_t ws_size,
                              hipStream_t stream)
{
    const float* x       = (const float*)d_in[0];
    const float* z       = (const float*)d_in[1];
    const float* weight  = (const float*)d_in[2];
    const float* w_alpha = (const float*)d_in[3];
    const float* b_alpha = (const float*)d_in[4];
    const float* w_beta  = (const float*)d_in[5];
    const float* b_beta  = (const float*)d_in[6];
    float* out = (float*)d_out;

    unsigned short* wfragB = (unsigned short*)d_ws;          // 2 x 512 KiB
    float* alpha = (float*)((char*)d_ws + 1048576);          // 4 KiB
    float* beta  = alpha + 2 * IN_F;                         // 4 KiB

    prep1_kernel<<<8, 256, 0, stream>>>(z, w_alpha, b_alpha, w_beta, b_beta,
                                        alpha, beta);
    prep2_kernel<<<512, 256, 0, stream>>>(weight, alpha, wfragB);
    modlin_kernel<<<8192, 512, 0, stream>>>(x, wfragB, beta, out);
}